// Round 2
// baseline (3458.892 us; speedup 1.0000x reference)
//
#include <hip/hip_runtime.h>
#include <hip/hip_bf16.h>

typedef unsigned short u16;
typedef unsigned int   u32;
typedef unsigned char  u8;

typedef __attribute__((ext_vector_type(8))) short bf16x8;
typedef __attribute__((ext_vector_type(4))) float f32x4;

static __device__ __forceinline__ float bf2f(u16 u){ return __uint_as_float(((u32)u)<<16); }
static __device__ __forceinline__ u16 f2bf(float f){
  u32 u = __float_as_uint(f);
  u32 r = (u + 0x7fff + ((u>>16)&1)) >> 16;   // RNE; inputs finite
  return (u16)r;
}

// fp8 e4m3 (OCP) helpers — HW cvt, saturating via pre-clamp
static __device__ __forceinline__ u8 f2fp8(float v){
  v = fminf(440.f, fmaxf(-440.f, v));
  return (u8)(__builtin_amdgcn_cvt_pk_fp8_f32(v, 0.f, 0, false) & 0xff);
}
static __device__ __forceinline__ u32 pk4_fp8(float a, float b, float c, float d){
  int w = __builtin_amdgcn_cvt_pk_fp8_f32(a, b, 0, false);
  w = __builtin_amdgcn_cvt_pk_fp8_f32(c, d, w, true);
  return (u32)w;
}

static __device__ __forceinline__ f32x4 mfma_bf16(bf16x8 a, bf16x8 b, f32x4 c){
  return __builtin_amdgcn_mfma_f32_16x16x32_bf16(a, b, c, 0, 0, 0);
}
static __device__ __forceinline__ f32x4 mfma_fp8(long a, long b, f32x4 c){
  return __builtin_amdgcn_mfma_f32_16x16x32_fp8_fp8(a, b, c, 0, 0, 0);
}
static __device__ __forceinline__ long lo64(uint4 v){ return (long)(((unsigned long long)v.y<<32) | v.x); }
static __device__ __forceinline__ long hi64(uint4 v){ return (long)(((unsigned long long)v.w<<32) | v.z); }

// ---------------------------------------------------------------------------
// K-w8: W f32 [m][k] -> fragment-major fp8 (16*W), 1KB-contiguous per (pt,ctg).
// grid (32,32,2), block 256.
// ---------------------------------------------------------------------------
__global__ void k_w8(const float* __restrict__ Wc, const float* __restrict__ Wd,
                     u8* __restrict__ Wc8, u8* __restrict__ Wd8){
  __shared__ float tile[64][65];
  const float* src = blockIdx.z ? Wd : Wc;
  u8* dst = blockIdx.z ? Wd8 : Wc8;
  const int m0 = blockIdx.x*64, k0 = blockIdx.y*64;
  const int t = threadIdx.x, r = t & 63, cc = t >> 6;
  #pragma unroll
  for (int j=0;j<4;j++){
    float4 v = *(const float4*)&src[(size_t)(m0+r)*2048 + k0 + cc*16 + j*4];
    tile[r][cc*16+j*4+0]=v.x; tile[r][cc*16+j*4+1]=v.y;
    tile[r][cc*16+j*4+2]=v.z; tile[r][cc*16+j*4+3]=v.w;
  }
  __syncthreads();
  u32 f0 = pk4_fp8(16.f*tile[cc*16+ 0][r], 16.f*tile[cc*16+ 1][r], 16.f*tile[cc*16+ 2][r], 16.f*tile[cc*16+ 3][r]);
  u32 f1 = pk4_fp8(16.f*tile[cc*16+ 4][r], 16.f*tile[cc*16+ 5][r], 16.f*tile[cc*16+ 6][r], 16.f*tile[cc*16+ 7][r]);
  u32 f2 = pk4_fp8(16.f*tile[cc*16+ 8][r], 16.f*tile[cc*16+ 9][r], 16.f*tile[cc*16+10][r], 16.f*tile[cc*16+11][r]);
  u32 f3 = pk4_fp8(16.f*tile[cc*16+12][r], 16.f*tile[cc*16+13][r], 16.f*tile[cc*16+14][r], 16.f*tile[cc*16+15][r]);
  const int k = k0 + r, mbase = m0 + cc*16;
  const int pt = mbase >> 6, half = (mbase >> 5) & 1, q0 = (mbase >> 3) & 3;
  const int ctg = k >> 4, lcv = k & 15;
  u8* dbase = dst + (size_t)((pt*128 + ctg)*64)*16 + half*8;
  *(uint2*)(dbase + (q0*16 + lcv)*16)     = make_uint2(f0, f1);
  *(uint2*)(dbase + ((q0+1)*16 + lcv)*16) = make_uint2(f2, f3);
}

// ---------------------------------------------------------------------------
// K-hcvt: h f32 [b][m][64] -> hb16 (bf16 row-major), hfm (bf16 frag-major B for
// phase 1), ht8p (fp8 frag-major B for phase 4). grid (32,16), block 256.
// ---------------------------------------------------------------------------
__global__ void k_hcvt(const float* __restrict__ h, u16* __restrict__ hb16,
                       u8* __restrict__ ht8p, u16* __restrict__ hfm){
  __shared__ float tile[64][65];
  const int k0 = blockIdx.x*64, b = blockIdx.y;
  const int t = threadIdx.x, r = t & 63, cc = t >> 6;
  const float* src = h + ((size_t)b*2048 + k0)*64;
  u32 hw[8];
  #pragma unroll
  for (int j=0;j<4;j++){
    float4 v = *(const float4*)&src[(size_t)r*64 + cc*16 + j*4];
    tile[r][cc*16+j*4+0]=v.x; tile[r][cc*16+j*4+1]=v.y;
    tile[r][cc*16+j*4+2]=v.z; tile[r][cc*16+j*4+3]=v.w;
    hw[2*j]   = (u32)f2bf(v.x) | ((u32)f2bf(v.y)<<16);
    hw[2*j+1] = (u32)f2bf(v.z) | ((u32)f2bf(v.w)<<16);
  }
  u16* hp = hb16 + (((size_t)b*2048 + k0 + r)*64 + cc*16);
  *(uint4*)hp     = make_uint4(hw[0],hw[1],hw[2],hw[3]);
  *(uint4*)(hp+8) = make_uint4(hw[4],hw[5],hw[6],hw[7]);
  __syncthreads();
  {
    u32 f0 = pk4_fp8(tile[cc*16+ 0][r], tile[cc*16+ 1][r], tile[cc*16+ 2][r], tile[cc*16+ 3][r]);
    u32 f1 = pk4_fp8(tile[cc*16+ 4][r], tile[cc*16+ 5][r], tile[cc*16+ 6][r], tile[cc*16+ 7][r]);
    u32 f2 = pk4_fp8(tile[cc*16+ 8][r], tile[cc*16+ 9][r], tile[cc*16+10][r], tile[cc*16+11][r]);
    u32 f3 = pk4_fp8(tile[cc*16+12][r], tile[cc*16+13][r], tile[cc*16+14][r], tile[cc*16+15][r]);
    const int pt = k0 >> 6, half = cc >> 1, q0 = (cc & 1)*2;
    const int ctg = r >> 4, lcv = r & 15;
    u8* dbase = ht8p + (size_t)b*131072 + (size_t)((pt*4 + ctg)*64)*16 + half*8;
    *(uint2*)(dbase + (q0*16 + lcv)*16)     = make_uint2(f0, f1);
    *(uint2*)(dbase + ((q0+1)*16 + lcv)*16) = make_uint2(f2, f3);
  }
  {
    const int col = k0 + r, ks = cc >> 1, q0 = (cc & 1)*2;
    const int ctg = col >> 4, lcv = col & 15;
    u16* fbase = hfm + (size_t)b*131072 + (size_t)ks*65536 + ((size_t)ctg*64)*8;
    #pragma unroll
    for (int qq=0; qq<2; ++qq){
      int q = q0 + qq;
      u32 p0 = (u32)f2bf(tile[r][ks*32+q*8+0]) | ((u32)f2bf(tile[r][ks*32+q*8+1])<<16);
      u32 p1 = (u32)f2bf(tile[r][ks*32+q*8+2]) | ((u32)f2bf(tile[r][ks*32+q*8+3])<<16);
      u32 p2 = (u32)f2bf(tile[r][ks*32+q*8+4]) | ((u32)f2bf(tile[r][ks*32+q*8+5])<<16);
      u32 p3 = (u32)f2bf(tile[r][ks*32+q*8+6]) | ((u32)f2bf(tile[r][ks*32+q*8+7])<<16);
      *(uint4*)(fbase + (size_t)(q*16 + lcv)*8) = make_uint4(p0,p1,p2,p3);
    }
  }
}

// ---------------------------------------------------------------------------
// K1: row n of A = E E^T. sign-mask (1 pos, 2 neg) + P=softmax(relu) bf16.
// ---------------------------------------------------------------------------
__global__ void k_P(const float* __restrict__ E, u16* __restrict__ P, u8* __restrict__ msk){
  __shared__ float Ew[16];
  __shared__ float arow[2048];
  __shared__ float red[4];
  const int t = threadIdx.x, n = blockIdx.x;
  if (t < 16) Ew[t] = E[n*16 + t];
  __syncthreads();
  float lmax = 0.f;
  for (int i=0;i<8;i++){
    int m = t + 256*i;
    const float* ep = E + m*16;
    float dot = 0.f;
    #pragma unroll
    for (int d=0; d<16; ++d) dot += Ew[d]*ep[d];
    msk[n*2048 + m] = dot > 0.f ? (u8)1 : (dot < 0.f ? (u8)2 : (u8)0);
    float ar = fmaxf(dot, 0.f);
    arow[m] = ar;
    lmax = fmaxf(lmax, ar);
  }
  for (int o=1;o<64;o<<=1) lmax = fmaxf(lmax, __shfl_xor(lmax, o));
  if ((t&63)==0) red[t>>6] = lmax;
  __syncthreads();
  float gmax = fmaxf(fmaxf(red[0],red[1]), fmaxf(red[2],red[3]));
  __syncthreads();
  float lsum = 0.f;
  for (int i=0;i<8;i++){
    int m = t + 256*i;
    float e = expf(arow[m] - gmax);
    arow[m] = e;
    lsum += e;
  }
  for (int o=1;o<64;o<<=1) lsum += __shfl_xor(lsum, o);
  if ((t&63)==0) red[t>>6] = lsum;
  __syncthreads();
  float inv = 1.f/(red[0]+red[1]+red[2]+red[3]);
  for (int i=0;i<8;i++){
    int m = t + 256*i;
    P[n*2048 + m] = f2bf(arow[m]*inv);
  }
}

// ---------------------------------------------------------------------------
// K-mbits: msk u8 [n][m] -> transposed bitmaps mp2/mn2 u32 [n/32][m].
// grid (2048, 8), block 256.
// ---------------------------------------------------------------------------
__global__ void k_mbits(const u8* __restrict__ msk, u32* __restrict__ mp2, u32* __restrict__ mn2){
  const int m = blockIdx.x, nb = blockIdx.y*256;
  const int t = threadIdx.x, w = t>>6, lane = t&63;
  u8 v = msk[(size_t)(nb + t)*2048 + m];
  unsigned long long bp = __ballot(v == (u8)1);
  unsigned long long bn = __ballot(v == (u8)2);
  if (lane == 0){
    int wi = (nb + w*64) >> 5;
    mp2[(size_t)wi*2048 + m]     = (u32)bp;
    mp2[(size_t)(wi+1)*2048 + m] = (u32)(bp>>32);
    mn2[(size_t)wi*2048 + m]     = (u32)bn;
    mn2[(size_t)(wi+1)*2048 + m] = (u32)(bn>>32);
  }
}

// ---------------------------------------------------------------------------
// K2x: c1x[b,n,c] = sum_m P[n,m] * x[b,m,c]
// ---------------------------------------------------------------------------
__global__ void k_c1x(const u16* __restrict__ P, const float* __restrict__ x, float* __restrict__ c1x){
  const int t = threadIdx.x;
  const int r = t>>1, c = t&1;
  const int n = blockIdx.x*64 + r, b = blockIdx.y;
  const u16* pr = P + (size_t)n*2048;
  const float* xb = x + (size_t)b*2048*2 + c;
  float acc = 0.f;
  for (int m=0;m<2048;m+=4){
    acc += bf2f(pr[m+0])*xb[(m+0)*2];
    acc += bf2f(pr[m+1])*xb[(m+1)*2];
    acc += bf2f(pr[m+2])*xb[(m+2)*2];
    acc += bf2f(pr[m+3])*xb[(m+3)*2];
  }
  c1x[((size_t)b*2048 + n)*2 + c] = acc;
}

// ---------------------------------------------------------------------------
// K2: Y[b,n,d] = sum_m P[n,m] * Z[b,m,d], Z f32 [B,N,64]. 64x64 tile.
// ---------------------------------------------------------------------------
__global__ void k_conv(const u16* __restrict__ P, const float* __restrict__ Z, float* __restrict__ Y){
  __shared__ float Pt[16][68];
  __shared__ float Zt[16][68];
  const int t = threadIdx.x;
  const int tr = t>>4, tc = t&15;
  const int n0 = blockIdx.x*64, b = blockIdx.y;
  float acc[4][4] = {};
  for (int mt=0; mt<128; ++mt){
    int m0 = mt*16;
    {
      int r = t>>2, c4 = (t&3)*4;
      const u16* pp = P + (size_t)(n0+r)*2048 + m0 + c4;
      u32 p0 = *(const u32*)pp, p1v = *(const u32*)(pp+2);
      Pt[c4+0][r]=bf2f((u16)p0);  Pt[c4+1][r]=bf2f((u16)(p0>>16));
      Pt[c4+2][r]=bf2f((u16)p1v); Pt[c4+3][r]=bf2f((u16)(p1v>>16));
      int mm = t>>4, d0 = (t&15)*4;
      float4 zv = *(const float4*)&Z[((size_t)b*2048 + m0+mm)*64 + d0];
      Zt[mm][d0+0]=zv.x; Zt[mm][d0+1]=zv.y; Zt[mm][d0+2]=zv.z; Zt[mm][d0+3]=zv.w;
    }
    __syncthreads();
    #pragma unroll
    for (int mm=0; mm<16; ++mm){
      float4 a  = *(const float4*)&Pt[mm][tr*4];
      float4 bz = *(const float4*)&Zt[mm][tc*4];
      acc[0][0]+=a.x*bz.x; acc[0][1]+=a.x*bz.y; acc[0][2]+=a.x*bz.z; acc[0][3]+=a.x*bz.w;
      acc[1][0]+=a.y*bz.x; acc[1][1]+=a.y*bz.y; acc[1][2]+=a.y*bz.z; acc[1][3]+=a.y*bz.w;
      acc[2][0]+=a.z*bz.x; acc[2][1]+=a.z*bz.y; acc[2][2]+=a.z*bz.z; acc[2][3]+=a.z*bz.w;
      acc[3][0]+=a.w*bz.x; acc[3][1]+=a.w*bz.y; acc[3][2]+=a.w*bz.z; acc[3][3]+=a.w*bz.w;
    }
    __syncthreads();
  }
  #pragma unroll
  for (int i=0;i<4;i++){
    float4 v = make_float4(acc[i][0],acc[i][1],acc[i][2],acc[i][3]);
    *(float4*)&Y[((size_t)b*2048 + n0 + tr*4 + i)*64 + tc*4] = v;
  }
}

// ---------------------------------------------------------------------------
// K3: gate SAGC -> zs = z*state, rws = r. One block per node n.
// ---------------------------------------------------------------------------
__global__ void k_gate(const float* __restrict__ E, const float* __restrict__ gw, const float* __restrict__ gb,
                       const float* __restrict__ x, const float* __restrict__ state,
                       const float* __restrict__ c1x, const float* __restrict__ c1s,
                       float* __restrict__ zs, float* __restrict__ rws){
  __shared__ float Ew[16];
  __shared__ float bnv[128];
  __shared__ float Wn[2][66][64];
  __shared__ float xg4[4][2][66];
  const int t = threadIdx.x, n = blockIdx.x;
  if (t < 16) Ew[t] = E[n*16 + t];
  __syncthreads();
  if (t < 128){
    float a = 0.f;
    #pragma unroll
    for (int e=0;e<16;e++) a += Ew[e]*gb[e*128 + t];
    bnv[t] = a;
  }
  for (int half=0; half<2; ++half){
    for (int idx=t; idx<8448; idx+=256){
      int o = idx & 63, rest = idx>>6, i = rest % 66, k = rest / 66;
      float a = 0.f;
      #pragma unroll
      for (int e=0;e<16;e++) a += Ew[e]*gw[((e*2+k)*66 + i)*128 + half*64 + o];
      Wn[k][i][o] = a;
    }
    __syncthreads();
    for (int bb=0; bb<4; ++bb){
      for (int idx=t; idx<528; idx+=256){
        int bi = idx/132, rem = idx%132, k = rem/66, i = rem%66;
        int b = bb*4 + bi;
        float v;
        if (k==0) v = (i<2) ? x[((size_t)b*2048+n)*2 + i] : state[((size_t)b*2048+n)*64 + (i-2)];
        else      v = (i<2) ? c1x[((size_t)b*2048+n)*2 + i] : c1s[((size_t)b*2048+n)*64 + (i-2)];
        xg4[bi][k][i] = v;
      }
      __syncthreads();
      {
        int bi = t>>6, o = t&63, b = bb*4 + bi;
        float a = 0.f;
        #pragma unroll
        for (int k=0;k<2;k++)
          for (int i=0;i<66;i++) a += xg4[bi][k][i]*Wn[k][i][o];
        a += bnv[half*64 + o];
        float s = 1.f/(1.f + expf(-a));
        if (half==0) zs[((size_t)b*2048+n)*64 + o] = s*state[((size_t)b*2048+n)*64 + o];
        else         rws[((size_t)b*2048+n)*64 + o] = s;
      }
      __syncthreads();
    }
  }
}

// ---------------------------------------------------------------------------
// K3b: update SAGC -> hc -> h = r*state + (1-r)*hc.
// ---------------------------------------------------------------------------
__global__ void k_upd(const float* __restrict__ E, const float* __restrict__ uw, const float* __restrict__ ub,
                      const float* __restrict__ x, const float* __restrict__ state,
                      const float* __restrict__ zs, const float* __restrict__ c1x, const float* __restrict__ c2s,
                      const float* __restrict__ rws, float* __restrict__ h){
  __shared__ float Ew[16];
  __shared__ float bnu[64];
  __shared__ float Wn[2][66][64];
  __shared__ float xg4[4][2][66];
  const int t = threadIdx.x, n = blockIdx.x;
  if (t < 16) Ew[t] = E[n*16 + t];
  __syncthreads();
  if (t < 64){
    float a = 0.f;
    #pragma unroll
    for (int e=0;e<16;e++) a += Ew[e]*ub[e*64 + t];
    bnu[t] = a;
  }
  for (int idx=t; idx<8448; idx+=256){
    int o = idx & 63, rest = idx>>6, i = rest % 66, k = rest / 66;
    float a = 0.f;
    #pragma unroll
    for (int e=0;e<16;e++) a += Ew[e]*uw[((e*2+k)*66 + i)*64 + o];
    Wn[k][i][o] = a;
  }
  __syncthreads();
  for (int bb=0; bb<4; ++bb){
    for (int idx=t; idx<528; idx+=256){
      int bi = idx/132, rem = idx%132, k = rem/66, i = rem%66;
      int b = bb*4 + bi;
      float v;
      if (k==0) v = (i<2) ? x[((size_t)b*2048+n)*2 + i] : zs[((size_t)b*2048+n)*64 + (i-2)];
      else      v = (i<2) ? c1x[((size_t)b*2048+n)*2 + i] : c2s[((size_t)b*2048+n)*64 + (i-2)];
      xg4[bi][k][i] = v;
    }
    __syncthreads();
    {
      int bi = t>>6, o = t&63, b = bb*4 + bi;
      float a = 0.f;
      #pragma unroll
      for (int k=0;k<2;k++)
        for (int i=0;i<66;i++) a += xg4[bi][k][i]*Wn[k][i][o];
      float hc = tanhf(a + bnu[o]);
      float rv = rws[((size_t)b*2048+n)*64 + o];
      h[((size_t)b*2048+n)*64 + o] = rv*state[((size_t)b*2048+n)*64 + o] + (1.f - rv)*hc;
    }
    __syncthreads();
  }
}

// ---------------------------------------------------------------------------
// K5: fused degrees, fp8 MFMA — ONE MASK PER DISPATCH.
// R9 change: 64-row blocks (512 blocks x 1024 thr, 16 waves, S = 64x2056 fp8 =
// 128.5 KB LDS, 1 block/CU, 4 waves/SIMD — same wave occupancy as R8's 2x512).
// Rationale: R8 was L1-port-bound — per-CU W traffic 16 MB over the dispatch
// needs ~50 B/cy at MFMA pace, ~80% of the L1 fill port -> queueing latency
// uncoverable. 64 rows/block halves W+hfm+hb16+ht8p on-chip traffic (~25 B/cy)
// and doubles phase-2 MFMA:byte (64 MFMA per 8 KB). Keeps R8's p0 rotation.
// fin=1: epilogue computes final output 0.8h - 0.1 oc + 0.1 od -> outp.
// ---------------------------------------------------------------------------
#define SROW8 2056

__global__ void __launch_bounds__(1024,4) k_deg(
    const u32* __restrict__ mbits, const u16* __restrict__ hb16,
    const u8* __restrict__ W8,
    const u8* __restrict__ ht8p, const u16* __restrict__ hfm,
    const float* __restrict__ hf32, const float* __restrict__ oc_in,
    float* __restrict__ outp, int fin){
  extern __shared__ u8 S[];
  __shared__ float redm[64][16];
  __shared__ float redsum[64][16];
  const int t = threadIdx.x;
  const int w = t >> 6, lane = t & 63, lc = lane & 15, q = lane >> 4;
  const int id = blockIdx.x;
  const int b = id >> 5, n0 = (id & 31) * 64;
  const int p0 = (id >> 3) & 31;          // per-CU-within-XCD rotation offset
  const u32* mrow0 = mbits + (size_t)(n0 >> 5)*2048;
  const u32* mrow1 = mrow0 + 2048;
  const u16* hbb = hb16 + (size_t)b*2048*64;
  const u16* hfb = hfm + (size_t)b*131072;
  const u8* htb = ht8p + (size_t)b*131072;

  // ---- phase 1: S[r][m] = fp8( (bit ? h_n.h_m : 0) / 8 ), pipelined ----
  // wave w owns ctgs [w*8, w*8+8) (128 cols), all 64 rows.
  {
    const int c0 = p0 & 7;
    bf16x8 A[4][2];
    #pragma unroll
    for (int rt=0; rt<4; ++rt)
      #pragma unroll
      for (int ks=0; ks<2; ++ks)
        A[rt][ks] = *(const bf16x8*)&hbb[(size_t)(n0 + rt*16 + lc)*64 + ks*32 + q*8];
    int ctg0 = w*8 + c0;
    bf16x8 B0c = *(const bf16x8*)(hfb + (size_t)ctg0*512 + lane*8);
    bf16x8 B1c = *(const bf16x8*)(hfb + 65536 + (size_t)ctg0*512 + lane*8);
    u32 m0c = mrow0[ctg0*16 + lc], m1c = mrow1[ctg0*16 + lc];
    #pragma unroll 1
    for (int ct=0; ct<8; ++ct){
      const int ctg  = w*8 + ((ct + c0) & 7);
      const int ctgn = w*8 + ((ct + 1 + c0) & 7);
      bf16x8 B0n = *(const bf16x8*)(hfb + (size_t)ctgn*512 + lane*8);
      bf16x8 B1n = *(const bf16x8*)(hfb + 65536 + (size_t)ctgn*512 + lane*8);
      u32 m0n = mrow0[ctgn*16 + lc], m1n = mrow1[ctgn*16 + lc];
      const int mcol = ctg*16 + lc;
      f32x4 a[4];
      #pragma unroll
      for (int rt=0; rt<4; ++rt){
        a[rt] = (f32x4){0.f,0.f,0.f,0.f};
        a[rt] = mfma_bf16(A[rt][0], B0c, a[rt]);
        a[rt] = mfma_bf16(A[rt][1], B1c, a[rt]);
      }
      #pragma unroll
      for (int rt=0; rt<4; ++rt){
        const u32 mw = (rt < 2) ? m0c : m1c;
        #pragma unroll
        for (int i=0;i<4;i++){
          const int row = rt*16 + q*4 + i;
          float v = ((mw >> (row & 31)) & 1u) ? a[rt][i]*0.125f : 0.f;
          S[row*SROW8 + mcol] = f2fp8(v);
        }
      }
      B0c = B0n; B1c = B1n; m0c = m0n; m1c = m1n;
    }
  }
  __syncthreads();

  // ---- phase 2: logits = S @ W ; wave owns k-cols [w*128, w*128+128) ----
  f32x4 acc[4][8];
  #pragma unroll
  for (int rt=0;rt<4;++rt)
    #pragma unroll
    for (int ct=0;ct<8;++ct) acc[rt][ct] = (f32x4){0.f,0.f,0.f,0.f};
  {
    const u8* wbase = W8 + (size_t)(w*8)*1024 + lane*16;
    uint4 bv[8];
    #pragma unroll
    for (int ct=0; ct<8; ++ct) bv[ct] = *(const uint4*)(wbase + (size_t)p0*131072 + ct*1024);
    #pragma unroll 1
    for (int pti=0; pti<32; ++pti){
      const int pt  = (pti + p0) & 31;
      const int ptn = (pti + 1 + p0) & 31;
      long ae[4], ao[4];
      #pragma unroll
      for (int rt=0; rt<4; ++rt){
        const u8* sp = S + (size_t)(rt*16 + lc)*SROW8 + q*8 + pt*64;
        ae[rt] = *(const long*)sp;
        ao[rt] = *(const long*)(sp + 32);
      }
      uint4 bn[8];
      #pragma unroll
      for (int ct=0; ct<8; ++ct) bn[ct] = *(const uint4*)(wbase + (size_t)ptn*131072 + ct*1024);
      #pragma unroll
      for (int ct=0; ct<8; ++ct){
        long be = lo64(bv[ct]), bo = hi64(bv[ct]);
        #pragma unroll
        for (int rt=0; rt<4; ++rt){
          acc[rt][ct] = mfma_fp8(ae[rt], be, acc[rt][ct]);
          acc[rt][ct] = mfma_fp8(ao[rt], bo, acc[rt][ct]);
        }
      }
      #pragma unroll
      for (int ct=0; ct<8; ++ct) bv[ct] = bn[ct];
    }
  }

  // ---- phase 3: row softmax over k (true logits = 0.5*acc) ----
  float gmax[4][4], gsc[4][4];
  #pragma unroll
  for (int rt=0; rt<4; ++rt)
    #pragma unroll
    for (int i=0;i<4;i++){
      float mx = acc[rt][0][i];
      #pragma unroll
      for (int ct=1; ct<8; ++ct) mx = fmaxf(mx, acc[rt][ct][i]);
      mx = fmaxf(mx, __shfl_xor(mx, 1));
      mx = fmaxf(mx, __shfl_xor(mx, 2));
      mx = fmaxf(mx, __shfl_xor(mx, 4));
      mx = fmaxf(mx, __shfl_xor(mx, 8));
      if (lc == 0) redm[rt*16 + q*4 + i][w] = mx;
    }
  __syncthreads();
  #pragma unroll
  for (int rt=0; rt<4; ++rt)
    #pragma unroll
    for (int i=0;i<4;i++){
      float m0 = redm[rt*16 + q*4 + i][0];
      #pragma unroll
      for (int j=1;j<16;j++) m0 = fmaxf(m0, redm[rt*16 + q*4 + i][j]);
      gmax[rt][i] = m0;
    }
  #pragma unroll
  for (int rt=0; rt<4; ++rt)
    #pragma unroll
    for (int i=0;i<4;i++){
      float s = 0.f;
      #pragma unroll
      for (int ct=0; ct<8; ++ct){
        float e = __expf(0.5f*(acc[rt][ct][i] - gmax[rt][i]));
        acc[rt][ct][i] = e;
        s += e;
      }
      s += __shfl_xor(s, 1);
      s += __shfl_xor(s, 2);
      s += __shfl_xor(s, 4);
      s += __shfl_xor(s, 8);
      if (lc == 0) redsum[rt*16 + q*4 + i][w] = s;
    }
  __syncthreads();
  #pragma unroll
  for (int rt=0; rt<4; ++rt)
    #pragma unroll
    for (int i=0;i<4;i++){
      float s = 0.f;
      #pragma unroll
      for (int j=0;j<16;j++) s += redsum[rt*16 + q*4 + i][j];
      gsc[rt][i] = 256.f/s;
    }
  #pragma unroll
  for (int ct=0; ct<8; ++ct){
    const int col = w*128 + ct*16 + lc;
    #pragma unroll
    for (int rt=0; rt<4; ++rt)
      #pragma unroll
      for (int i=0;i<4;i++)
        S[(rt*16 + q*4 + i)*SROW8 + col] = f2fp8(acc[rt][ct][i]*gsc[rt][i]);
  }
  __syncthreads();

  // ---- phase 4: out = (deg*256) @ h / 256, pipelined; fin fuses k_final ----
  {
    const int rt4 = w >> 2, dt = w & 3;   // 16 waves = 4 row-tiles x 4 d-tiles
    f32x4 o = {0.f,0.f,0.f,0.f};
    const u8* abase = S + (size_t)(rt4*16 + lc)*SROW8 + q*8;
    const u8* bbase = htb + (size_t)dt*1024 + lane*16;
    uint4 bcur = *(const uint4*)(bbase + (size_t)p0*4096);
    #pragma unroll 1
    for (int pti=0; pti<32; ++pti){
      const int pt = (pti + p0) & 31;
      uint4 bnxt = *(const uint4*)(bbase + (size_t)((pti + 1 + p0)&31)*4096);
      long ae = *(const long*)(abase + pt*64);
      long ao = *(const long*)(abase + pt*64 + 32);
      o = mfma_fp8(ae, lo64(bcur), o);
      o = mfma_fp8(ao, hi64(bcur), o);
      bcur = bnxt;
    }
    float* op = outp + (size_t)b*2048*64;
    const float* hp = hf32 + (size_t)b*2048*64;
    const float* cp = oc_in + (size_t)b*2048*64;
    #pragma unroll
    for (int i=0;i<4;i++){
      size_t idx = (size_t)(n0 + rt4*16 + q*4 + i)*64 + dt*16 + lc;
      float v = o[i]*(1.f/256.f);
      if (fin) v = 0.8f*hp[idx] - 0.1f*cp[idx] + 0.1f*v;
      op[idx] = v;
    }
  }
}

// ---------------------------------------------------------------------------
extern "C" void kernel_launch(void* const* d_in, const int* in_sizes, int n_in,
                              void* d_out, int out_size, void* d_ws, size_t ws_size,
                              hipStream_t stream) {
  const float* x     = (const float*)d_in[0];
  const float* state = (const float*)d_in[1];
  const float* E     = (const float*)d_in[2];
  const float* Wc    = (const float*)d_in[3];
  const float* Wd    = (const float*)d_in[4];
  const float* gw    = (const float*)d_in[5];
  const float* gb    = (const float*)d_in[6];
  const float* uw    = (const float*)d_in[7];
  const float* ub    = (const float*)d_in[8];

  // workspace layout (bytes). Total 73,662,464 B = 70.2 MB.
  char* base = (char*)d_ws;
  u16*   P    = (u16*)(base + 0);           //  8,388,608  (dead after 2nd k_conv)
  u32*   mp2  = (u32*)(base + 0);           //    524,288  (aliases P; written after P dead)
  u32*   mn2  = (u32*)(base + 524288);      //    524,288  (aliases P)
  u8*    msk  = (u8*) (base + 8388608);     //  4,194,304
  u8*    Wc8  = (u8*) (base + 12582912);    //  4,194,304
  u8*    Wd8  = (u8*) (base + 16777216);    //  4,194,304
  u16*   hb16 = (u16*)(base + 20971520);    //  4,194,304
  u8*    ht8p = (u8*) (base + 25165824);    //  2,097,152
  u16*   hfm  = (u16*)(base + 27262976);    //  4,194,304
  float* c1x  = (float*)(base + 31457280);  //    262,144
  float* c1s  = (float*)(base + 31719424);  //  8,388,608
  float* zs   = (float*)(base + 40108032);  //  8,388,608
  float* rws  = (float*)(base + 48496640);  //  8,388,608
  float* c2s  = (float*)(base + 56885248);  //  8,388,608
  float* h    = (float*)(base + 65273856);  //  8,388,608
  float* oc   = c1s;                        // dead after k_gate
  float* od   = c2s;                        // dead after k_upd (unused placeholder)

  k_w8<<<dim3(32,32,2), 256, 0, stream>>>(Wc, Wd, Wc8, Wd8);
  k_P<<<2048, 256, 0, stream>>>(E, P, msk);
  k_c1x<<<dim3(32,16), 128, 0, stream>>>(P, x, c1x);
  k_conv<<<dim3(32,16), 256, 0, stream>>>(P, state, c1s);
  k_gate<<<2048, 256, 0, stream>>>(E, gw, gb, x, state, c1x, c1s, zs, rws);
  k_conv<<<dim3(32,16), 256, 0, stream>>>(P, zs, c2s);
  k_upd<<<2048, 256, 0, stream>>>(E, uw, ub, x, state, zs, c1x, c2s, rws, h);
  k_hcvt<<<dim3(32,16), 256, 0, stream>>>(h, hb16, ht8p, hfm);
  k_mbits<<<dim3(2048,8), 256, 0, stream>>>(msk, mp2, mn2);   // P dead by now

  const int deg_lds = 64*SROW8;   // 131,584 B dynamic (+8 KB static red arrays)
  hipFuncSetAttribute((const void*)k_deg, hipFuncAttributeMaxDynamicSharedMemorySize, deg_lds);
  // dispatch 1: connect mask — only Wc8 hot in every XCD L2
  k_deg<<<512, 1024, deg_lds, stream>>>(mp2, hb16, Wc8, ht8p, hfm, h, h, oc, 0);
  // dispatch 2: disconnect mask — only Wd8 hot; fused final epilogue -> d_out
  k_deg<<<512, 1024, deg_lds, stream>>>(mn2, hb16, Wd8, ht8p, hfm, h, oc, (float*)d_out, 1);
}

// Round 3
// 1384.214 us; speedup vs baseline: 2.4988x; 2.4988x over previous
//
#include <hip/hip_runtime.h>
#include <hip/hip_bf16.h>

typedef unsigned short u16;
typedef unsigned int   u32;
typedef unsigned char  u8;

typedef __attribute__((ext_vector_type(8))) short bf16x8;
typedef __attribute__((ext_vector_type(4))) float f32x4;
typedef __attribute__((ext_vector_type(16))) float f32x16;

static __device__ __forceinline__ float bf2f(u16 u){ return __uint_as_float(((u32)u)<<16); }
static __device__ __forceinline__ u16 f2bf(float f){
  u32 u = __float_as_uint(f);
  u32 r = (u + 0x7fff + ((u>>16)&1)) >> 16;   // RNE; inputs finite
  return (u16)r;
}

// fp8 e4m3 (OCP) helpers — HW cvt, saturating via pre-clamp
static __device__ __forceinline__ u8 f2fp8(float v){
  v = fminf(440.f, fmaxf(-440.f, v));
  return (u8)(__builtin_amdgcn_cvt_pk_fp8_f32(v, 0.f, 0, false) & 0xff);
}
static __device__ __forceinline__ u32 pk4_fp8(float a, float b, float c, float d){
  int w = __builtin_amdgcn_cvt_pk_fp8_f32(a, b, 0, false);
  w = __builtin_amdgcn_cvt_pk_fp8_f32(c, d, w, true);
  return (u32)w;
}

static __device__ __forceinline__ f32x4 mfma_bf16(bf16x8 a, bf16x8 b, f32x4 c){
  return __builtin_amdgcn_mfma_f32_16x16x32_bf16(a, b, c, 0, 0, 0);
}
static __device__ __forceinline__ f32x4 mfma_fp8(long a, long b, f32x4 c){
  return __builtin_amdgcn_mfma_f32_16x16x32_fp8_fp8(a, b, c, 0, 0, 0);
}
static __device__ __forceinline__ f32x16 mfma_fp8_32(long a, long b, f32x16 c){
  return __builtin_amdgcn_mfma_f32_32x32x16_fp8_fp8(a, b, c, 0, 0, 0);
}
static __device__ __forceinline__ long lo64(uint4 v){ return (long)(((unsigned long long)v.y<<32) | v.x); }
static __device__ __forceinline__ long hi64(uint4 v){ return (long)(((unsigned long long)v.w<<32) | v.z); }

// ---------------------------------------------------------------------------
// K-w8: W f32 [m][k] -> fp8 packed for 32x32x16 B-fragments.
// Layout: 1KB block per (pt = m/64, kt = k/32, mcp = (m/32)&1):
//   addr = ((pt*64 + kt)*2 + mcp)*1024 + lane*16 + sel*8 + j
//   element = W[pt*64 + (mcp*2+sel)*16 + (lane>>5)*8 + j][kt*32 + (lane&31)]
// grid (32,32,2), block 256.
// ---------------------------------------------------------------------------
__global__ void k_w8(const float* __restrict__ Wc, const float* __restrict__ Wd,
                     u8* __restrict__ Wc8, u8* __restrict__ Wd8){
  __shared__ float tile[64][65];
  const float* src = blockIdx.z ? Wd : Wc;
  u8* dst = blockIdx.z ? Wd8 : Wc8;
  const int m0 = blockIdx.x*64, k0 = blockIdx.y*64;
  const int t = threadIdx.x, r = t & 63, cc = t >> 6;
  #pragma unroll
  for (int j=0;j<4;j++){
    float4 v = *(const float4*)&src[(size_t)(m0+r)*2048 + k0 + cc*16 + j*4];
    tile[r][cc*16+j*4+0]=v.x; tile[r][cc*16+j*4+1]=v.y;
    tile[r][cc*16+j*4+2]=v.z; tile[r][cc*16+j*4+3]=v.w;
  }
  __syncthreads();
  const int lane = t & 63, sub = t >> 6;     // sub 0..3
  const int kth = sub & 1, mcp = sub >> 1;
  const int kl = kth*32 + (lane & 31);       // k within 64-tile
  const int ml = mcp*32 + (lane >> 5)*8;     // m base within 64-tile
  u32 b0 = pk4_fp8(16.f*tile[ml+ 0][kl], 16.f*tile[ml+ 1][kl], 16.f*tile[ml+ 2][kl], 16.f*tile[ml+ 3][kl]);
  u32 b1 = pk4_fp8(16.f*tile[ml+ 4][kl], 16.f*tile[ml+ 5][kl], 16.f*tile[ml+ 6][kl], 16.f*tile[ml+ 7][kl]);
  u32 b2 = pk4_fp8(16.f*tile[ml+16][kl], 16.f*tile[ml+17][kl], 16.f*tile[ml+18][kl], 16.f*tile[ml+19][kl]);
  u32 b3 = pk4_fp8(16.f*tile[ml+20][kl], 16.f*tile[ml+21][kl], 16.f*tile[ml+22][kl], 16.f*tile[ml+23][kl]);
  const int pt = m0 >> 6, kt = (k0 >> 5) + kth;
  u8* dbase = dst + (size_t)((pt*64 + kt)*2 + mcp)*1024 + lane*16;
  *(uint4*)dbase = make_uint4(b0, b1, b2, b3);
}

// ---------------------------------------------------------------------------
// K-hcvt: h f32 [b][m][64] -> hb16 (bf16 row-major), hfm (bf16 frag-major B for
// phase 1), ht8p (fp8 frag-major B for phase 4). grid (32,16), block 256.
// ---------------------------------------------------------------------------
__global__ void k_hcvt(const float* __restrict__ h, u16* __restrict__ hb16,
                       u8* __restrict__ ht8p, u16* __restrict__ hfm){
  __shared__ float tile[64][65];
  const int k0 = blockIdx.x*64, b = blockIdx.y;
  const int t = threadIdx.x, r = t & 63, cc = t >> 6;
  const float* src = h + ((size_t)b*2048 + k0)*64;
  u32 hw[8];
  #pragma unroll
  for (int j=0;j<4;j++){
    float4 v = *(const float4*)&src[(size_t)r*64 + cc*16 + j*4];
    tile[r][cc*16+j*4+0]=v.x; tile[r][cc*16+j*4+1]=v.y;
    tile[r][cc*16+j*4+2]=v.z; tile[r][cc*16+j*4+3]=v.w;
    hw[2*j]   = (u32)f2bf(v.x) | ((u32)f2bf(v.y)<<16);
    hw[2*j+1] = (u32)f2bf(v.z) | ((u32)f2bf(v.w)<<16);
  }
  u16* hp = hb16 + (((size_t)b*2048 + k0 + r)*64 + cc*16);
  *(uint4*)hp     = make_uint4(hw[0],hw[1],hw[2],hw[3]);
  *(uint4*)(hp+8) = make_uint4(hw[4],hw[5],hw[6],hw[7]);
  __syncthreads();
  {
    u32 f0 = pk4_fp8(tile[cc*16+ 0][r], tile[cc*16+ 1][r], tile[cc*16+ 2][r], tile[cc*16+ 3][r]);
    u32 f1 = pk4_fp8(tile[cc*16+ 4][r], tile[cc*16+ 5][r], tile[cc*16+ 6][r], tile[cc*16+ 7][r]);
    u32 f2 = pk4_fp8(tile[cc*16+ 8][r], tile[cc*16+ 9][r], tile[cc*16+10][r], tile[cc*16+11][r]);
    u32 f3 = pk4_fp8(tile[cc*16+12][r], tile[cc*16+13][r], tile[cc*16+14][r], tile[cc*16+15][r]);
    const int pt = k0 >> 6, half = cc >> 1, q0 = (cc & 1)*2;
    const int ctg = r >> 4, lcv = r & 15;
    u8* dbase = ht8p + (size_t)b*131072 + (size_t)((pt*4 + ctg)*64)*16 + half*8;
    *(uint2*)(dbase + (q0*16 + lcv)*16)     = make_uint2(f0, f1);
    *(uint2*)(dbase + ((q0+1)*16 + lcv)*16) = make_uint2(f2, f3);
  }
  {
    const int col = k0 + r, ks = cc >> 1, q0 = (cc & 1)*2;
    const int ctg = col >> 4, lcv = col & 15;
    u16* fbase = hfm + (size_t)b*131072 + (size_t)ks*65536 + ((size_t)ctg*64)*8;
    #pragma unroll
    for (int qq=0; qq<2; ++qq){
      int q = q0 + qq;
      u32 p0 = (u32)f2bf(tile[r][ks*32+q*8+0]) | ((u32)f2bf(tile[r][ks*32+q*8+1])<<16);
      u32 p1 = (u32)f2bf(tile[r][ks*32+q*8+2]) | ((u32)f2bf(tile[r][ks*32+q*8+3])<<16);
      u32 p2 = (u32)f2bf(tile[r][ks*32+q*8+4]) | ((u32)f2bf(tile[r][ks*32+q*8+5])<<16);
      u32 p3 = (u32)f2bf(tile[r][ks*32+q*8+6]) | ((u32)f2bf(tile[r][ks*32+q*8+7])<<16);
      *(uint4*)(fbase + (size_t)(q*16 + lcv)*8) = make_uint4(p0,p1,p2,p3);
    }
  }
}

// ---------------------------------------------------------------------------
// K1: row n of A = E E^T. sign-mask (1 pos, 2 neg) + P=softmax(relu) bf16.
// ---------------------------------------------------------------------------
__global__ void k_P(const float* __restrict__ E, u16* __restrict__ P, u8* __restrict__ msk){
  __shared__ float Ew[16];
  __shared__ float arow[2048];
  __shared__ float red[4];
  const int t = threadIdx.x, n = blockIdx.x;
  if (t < 16) Ew[t] = E[n*16 + t];
  __syncthreads();
  float lmax = 0.f;
  for (int i=0;i<8;i++){
    int m = t + 256*i;
    const float* ep = E + m*16;
    float dot = 0.f;
    #pragma unroll
    for (int d=0; d<16; ++d) dot += Ew[d]*ep[d];
    msk[n*2048 + m] = dot > 0.f ? (u8)1 : (dot < 0.f ? (u8)2 : (u8)0);
    float ar = fmaxf(dot, 0.f);
    arow[m] = ar;
    lmax = fmaxf(lmax, ar);
  }
  for (int o=1;o<64;o<<=1) lmax = fmaxf(lmax, __shfl_xor(lmax, o));
  if ((t&63)==0) red[t>>6] = lmax;
  __syncthreads();
  float gmax = fmaxf(fmaxf(red[0],red[1]), fmaxf(red[2],red[3]));
  __syncthreads();
  float lsum = 0.f;
  for (int i=0;i<8;i++){
    int m = t + 256*i;
    float e = expf(arow[m] - gmax);
    arow[m] = e;
    lsum += e;
  }
  for (int o=1;o<64;o<<=1) lsum += __shfl_xor(lsum, o);
  if ((t&63)==0) red[t>>6] = lsum;
  __syncthreads();
  float inv = 1.f/(red[0]+red[1]+red[2]+red[3]);
  for (int i=0;i<8;i++){
    int m = t + 256*i;
    P[n*2048 + m] = f2bf(arow[m]*inv);
  }
}

// ---------------------------------------------------------------------------
// K-mbits: msk u8 [n][m] -> transposed bitmaps mp2/mn2 u32 [n/32][m].
// grid (2048, 8), block 256.
// ---------------------------------------------------------------------------
__global__ void k_mbits(const u8* __restrict__ msk, u32* __restrict__ mp2, u32* __restrict__ mn2){
  const int m = blockIdx.x, nb = blockIdx.y*256;
  const int t = threadIdx.x, w = t>>6, lane = t&63;
  u8 v = msk[(size_t)(nb + t)*2048 + m];
  unsigned long long bp = __ballot(v == (u8)1);
  unsigned long long bn = __ballot(v == (u8)2);
  if (lane == 0){
    int wi = (nb + w*64) >> 5;
    mp2[(size_t)wi*2048 + m]     = (u32)bp;
    mp2[(size_t)(wi+1)*2048 + m] = (u32)(bp>>32);
    mn2[(size_t)wi*2048 + m]     = (u32)bn;
    mn2[(size_t)(wi+1)*2048 + m] = (u32)(bn>>32);
  }
}

// ---------------------------------------------------------------------------
// K2x: c1x[b,n,c] = sum_m P[n,m] * x[b,m,c]
// ---------------------------------------------------------------------------
__global__ void k_c1x(const u16* __restrict__ P, const float* __restrict__ x, float* __restrict__ c1x){
  const int t = threadIdx.x;
  const int r = t>>1, c = t&1;
  const int n = blockIdx.x*64 + r, b = blockIdx.y;
  const u16* pr = P + (size_t)n*2048;
  const float* xb = x + (size_t)b*2048*2 + c;
  float acc = 0.f;
  for (int m=0;m<2048;m+=4){
    acc += bf2f(pr[m+0])*xb[(m+0)*2];
    acc += bf2f(pr[m+1])*xb[(m+1)*2];
    acc += bf2f(pr[m+2])*xb[(m+2)*2];
    acc += bf2f(pr[m+3])*xb[(m+3)*2];
  }
  c1x[((size_t)b*2048 + n)*2 + c] = acc;
}

// ---------------------------------------------------------------------------
// K2: Y[b,n,d] = sum_m P[n,m] * Z[b,m,d], Z f32 [B,N,64]. 64x64 tile.
// ---------------------------------------------------------------------------
__global__ void k_conv(const u16* __restrict__ P, const float* __restrict__ Z, float* __restrict__ Y){
  __shared__ float Pt[16][68];
  __shared__ float Zt[16][68];
  const int t = threadIdx.x;
  const int tr = t>>4, tc = t&15;
  const int n0 = blockIdx.x*64, b = blockIdx.y;
  float acc[4][4] = {};
  for (int mt=0; mt<128; ++mt){
    int m0 = mt*16;
    {
      int r = t>>2, c4 = (t&3)*4;
      const u16* pp = P + (size_t)(n0+r)*2048 + m0 + c4;
      u32 p0 = *(const u32*)pp, p1v = *(const u32*)(pp+2);
      Pt[c4+0][r]=bf2f((u16)p0);  Pt[c4+1][r]=bf2f((u16)(p0>>16));
      Pt[c4+2][r]=bf2f((u16)p1v); Pt[c4+3][r]=bf2f((u16)(p1v>>16));
      int mm = t>>4, d0 = (t&15)*4;
      float4 zv = *(const float4*)&Z[((size_t)b*2048 + m0+mm)*64 + d0];
      Zt[mm][d0+0]=zv.x; Zt[mm][d0+1]=zv.y; Zt[mm][d0+2]=zv.z; Zt[mm][d0+3]=zv.w;
    }
    __syncthreads();
    #pragma unroll
    for (int mm=0; mm<16; ++mm){
      float4 a  = *(const float4*)&Pt[mm][tr*4];
      float4 bz = *(const float4*)&Zt[mm][tc*4];
      acc[0][0]+=a.x*bz.x; acc[0][1]+=a.x*bz.y; acc[0][2]+=a.x*bz.z; acc[0][3]+=a.x*bz.w;
      acc[1][0]+=a.y*bz.x; acc[1][1]+=a.y*bz.y; acc[1][2]+=a.y*bz.z; acc[1][3]+=a.y*bz.w;
      acc[2][0]+=a.z*bz.x; acc[2][1]+=a.z*bz.y; acc[2][2]+=a.z*bz.z; acc[2][3]+=a.z*bz.w;
      acc[3][0]+=a.w*bz.x; acc[3][1]+=a.w*bz.y; acc[3][2]+=a.w*bz.z; acc[3][3]+=a.w*bz.w;
    }
    __syncthreads();
  }
  #pragma unroll
  for (int i=0;i<4;i++){
    float4 v = make_float4(acc[i][0],acc[i][1],acc[i][2],acc[i][3]);
    *(float4*)&Y[((size_t)b*2048 + n0 + tr*4 + i)*64 + tc*4] = v;
  }
}

// ---------------------------------------------------------------------------
// K3: gate SAGC -> zs = z*state, rws = r. One block per node n.
// ---------------------------------------------------------------------------
__global__ void k_gate(const float* __restrict__ E, const float* __restrict__ gw, const float* __restrict__ gb,
                       const float* __restrict__ x, const float* __restrict__ state,
                       const float* __restrict__ c1x, const float* __restrict__ c1s,
                       float* __restrict__ zs, float* __restrict__ rws){
  __shared__ float Ew[16];
  __shared__ float bnv[128];
  __shared__ float Wn[2][66][64];
  __shared__ float xg4[4][2][66];
  const int t = threadIdx.x, n = blockIdx.x;
  if (t < 16) Ew[t] = E[n*16 + t];
  __syncthreads();
  if (t < 128){
    float a = 0.f;
    #pragma unroll
    for (int e=0;e<16;e++) a += Ew[e]*gb[e*128 + t];
    bnv[t] = a;
  }
  for (int half=0; half<2; ++half){
    for (int idx=t; idx<8448; idx+=256){
      int o = idx & 63, rest = idx>>6, i = rest % 66, k = rest / 66;
      float a = 0.f;
      #pragma unroll
      for (int e=0;e<16;e++) a += Ew[e]*gw[((e*2+k)*66 + i)*128 + half*64 + o];
      Wn[k][i][o] = a;
    }
    __syncthreads();
    for (int bb=0; bb<4; ++bb){
      for (int idx=t; idx<528; idx+=256){
        int bi = idx/132, rem = idx%132, k = rem/66, i = rem%66;
        int b = bb*4 + bi;
        float v;
        if (k==0) v = (i<2) ? x[((size_t)b*2048+n)*2 + i] : state[((size_t)b*2048+n)*64 + (i-2)];
        else      v = (i<2) ? c1x[((size_t)b*2048+n)*2 + i] : c1s[((size_t)b*2048+n)*64 + (i-2)];
        xg4[bi][k][i] = v;
      }
      __syncthreads();
      {
        int bi = t>>6, o = t&63, b = bb*4 + bi;
        float a = 0.f;
        #pragma unroll
        for (int k=0;k<2;k++)
          for (int i=0;i<66;i++) a += xg4[bi][k][i]*Wn[k][i][o];
        a += bnv[half*64 + o];
        float s = 1.f/(1.f + expf(-a));
        if (half==0) zs[((size_t)b*2048+n)*64 + o] = s*state[((size_t)b*2048+n)*64 + o];
        else         rws[((size_t)b*2048+n)*64 + o] = s;
      }
      __syncthreads();
    }
  }
}

// ---------------------------------------------------------------------------
// K3b: update SAGC -> hc -> h = r*state + (1-r)*hc.
// ---------------------------------------------------------------------------
__global__ void k_upd(const float* __restrict__ E, const float* __restrict__ uw, const float* __restrict__ ub,
                      const float* __restrict__ x, const float* __restrict__ state,
                      const float* __restrict__ zs, const float* __restrict__ c1x, const float* __restrict__ c2s,
                      const float* __restrict__ rws, float* __restrict__ h){
  __shared__ float Ew[16];
  __shared__ float bnu[64];
  __shared__ float Wn[2][66][64];
  __shared__ float xg4[4][2][66];
  const int t = threadIdx.x, n = blockIdx.x;
  if (t < 16) Ew[t] = E[n*16 + t];
  __syncthreads();
  if (t < 64){
    float a = 0.f;
    #pragma unroll
    for (int e=0;e<16;e++) a += Ew[e]*ub[e*64 + t];
    bnu[t] = a;
  }
  for (int idx=t; idx<8448; idx+=256){
    int o = idx & 63, rest = idx>>6, i = rest % 66, k = rest / 66;
    float a = 0.f;
    #pragma unroll
    for (int e=0;e<16;e++) a += Ew[e]*uw[((e*2+k)*66 + i)*64 + o];
    Wn[k][i][o] = a;
  }
  __syncthreads();
  for (int bb=0; bb<4; ++bb){
    for (int idx=t; idx<528; idx+=256){
      int bi = idx/132, rem = idx%132, k = rem/66, i = rem%66;
      int b = bb*4 + bi;
      float v;
      if (k==0) v = (i<2) ? x[((size_t)b*2048+n)*2 + i] : zs[((size_t)b*2048+n)*64 + (i-2)];
      else      v = (i<2) ? c1x[((size_t)b*2048+n)*2 + i] : c2s[((size_t)b*2048+n)*64 + (i-2)];
      xg4[bi][k][i] = v;
    }
    __syncthreads();
    {
      int bi = t>>6, o = t&63, b = bb*4 + bi;
      float a = 0.f;
      #pragma unroll
      for (int k=0;k<2;k++)
        for (int i=0;i<66;i++) a += xg4[bi][k][i]*Wn[k][i][o];
      float hc = tanhf(a + bnu[o]);
      float rv = rws[((size_t)b*2048+n)*64 + o];
      h[((size_t)b*2048+n)*64 + o] = rv*state[((size_t)b*2048+n)*64 + o] + (1.f - rv)*hc;
    }
    __syncthreads();
  }
}

// ---------------------------------------------------------------------------
// K5: fused degrees — R10: phase 2 on 32x32x16 fp8 MFMA (half the instruction
// count of R8's 16x16x32) + dependency-distance reordering everywhere.
// Theory: R8's 617us >> 134us pipe floor with no saturated resource = MFMA
// dep/issue serialization at 2 waves/SIMD. dist-2 acc chains -> dist-4..8;
// phase-4 serial 64-chain -> 2 interleaved 32-chains.
// Geometry = R8: grid 1024 (b*64 + n0/32), 512 thr, S = 32x2056 fp8 LDS,
// p0 rotation kept. fin=1 fuses final epilogue.
// ---------------------------------------------------------------------------
#define SROW8 2056

__global__ void __launch_bounds__(512,2) k_deg(
    const u32* __restrict__ mbits, const u16* __restrict__ hb16,
    const u8* __restrict__ W8,
    const u8* __restrict__ ht8p, const u16* __restrict__ hfm,
    const float* __restrict__ hf32, const float* __restrict__ oc_in,
    float* __restrict__ outp, int fin){
  extern __shared__ u8 S[];
  __shared__ float redm[32][8];
  __shared__ float redsum[32][8];
  const int t = threadIdx.x;
  const int w = t >> 6, lane = t & 63, lc = lane & 15, q = lane >> 4;
  const int l32 = lane & 31, h32 = lane >> 5;
  const int id = blockIdx.x;
  const int b = id >> 6, n0 = (id & 63) * 32;
  const int p0 = (id >> 3) & 31;          // per-CU-within-XCD rotation offset
  const u32* mrow = mbits + (size_t)(n0 >> 5)*2048;
  const u16* hbb = hb16 + (size_t)b*2048*64;
  const u16* hfb = hfm + (size_t)b*131072;
  const u8* htb = ht8p + (size_t)b*131072;

  // ---- phase 1: S[r][m] = fp8( (bit ? h_n.h_m : 0) / 8 ), pipelined ----
  {
    const int c0 = p0 & 15;
    bf16x8 A[2][2];
    #pragma unroll
    for (int rt=0; rt<2; ++rt)
      #pragma unroll
      for (int ks=0; ks<2; ++ks)
        A[rt][ks] = *(const bf16x8*)&hbb[(size_t)(n0 + rt*16 + lc)*64 + ks*32 + q*8];
    int ctg0 = w*16 + c0;
    bf16x8 B0c = *(const bf16x8*)(hfb + (size_t)ctg0*512 + lane*8);
    bf16x8 B1c = *(const bf16x8*)(hfb + 65536 + (size_t)ctg0*512 + lane*8);
    u32 mbc = mrow[ctg0*16 + lc];
    #pragma unroll 1
    for (int ct=0; ct<16; ++ct){
      const int ctg = w*16 + ((ct + c0) & 15);
      const int ctgn = w*16 + ((ct + 1 + c0) & 15);
      bf16x8 B0n = *(const bf16x8*)(hfb + (size_t)ctgn*512 + lane*8);
      bf16x8 B1n = *(const bf16x8*)(hfb + 65536 + (size_t)ctgn*512 + lane*8);
      u32 mbn = mrow[ctgn*16 + lc];
      const int mcol = ctg*16 + lc;
      f32x4 a0 = {0.f,0.f,0.f,0.f}, a1 = {0.f,0.f,0.f,0.f};
      a0 = mfma_bf16(A[0][0], B0c, a0);
      a1 = mfma_bf16(A[1][0], B0c, a1);
      a0 = mfma_bf16(A[0][1], B1c, a0);
      a1 = mfma_bf16(A[1][1], B1c, a1);
      #pragma unroll
      for (int i=0;i<4;i++){
        int r0 = q*4 + i, r1 = 16 + q*4 + i;
        float v0 = ((mbc >> r0) & 1u) ? a0[i]*0.125f : 0.f;
        float v1 = ((mbc >> r1) & 1u) ? a1[i]*0.125f : 0.f;
        S[r0*SROW8 + mcol] = f2fp8(v0);
        S[r1*SROW8 + mcol] = f2fp8(v1);
      }
      B0c = B0n; B1c = B1n; mbc = mbn;
    }
  }
  __syncthreads();

  // ---- phase 2: logits = S @ W via 32x32x16 fp8; wave owns k-cols
  // [w*256, w*256+256) = col-tiles kt in [w*8, w*8+8). ----
  f32x16 acc[8];
  #pragma unroll
  for (int tt=0;tt<8;++tt) acc[tt] = (f32x16)(0.f);
  {
    // A-frag addr: row = lane&31, m = pt*64 + s*16 + (lane>>5)*8
    const u8* abase = S + (size_t)l32*SROW8 + h32*8;
    // B blocks: ((pt*64 + kt)*2 + mcp)*1024; wave kt base = w*8.
    const u8* wbase = W8 + (size_t)(w*8)*2048 + lane*16;
    uint4 bv[8];
    #pragma unroll
    for (int i=0; i<8; ++i) bv[i] = *(const uint4*)(wbase + (size_t)p0*131072 + i*1024);
    #pragma unroll 1
    for (int pti=0; pti<32; ++pti){
      const int pt  = (pti + p0) & 31;
      const int ptn = (pti + 1 + p0) & 31;
      long a[4];
      #pragma unroll
      for (int s=0; s<4; ++s) a[s] = *(const long*)(abase + pt*64 + s*16);
      const u8* wcur = wbase + (size_t)pt*131072;
      const u8* wnxt = wbase + (size_t)ptn*131072;
      uint4 bw[8];
      #pragma unroll
      for (int i=0; i<8; ++i) bw[i] = *(const uint4*)(wcur + (8+i)*1024);
      // first half: kt8 0..3 (blocks bv[kt8*2 + mcp]); s = mcp*2 + sel
      #pragma unroll
      for (int s=0; s<4; ++s){
        #pragma unroll
        for (int k4=0; k4<4; ++k4){
          long bb = (s & 1) ? hi64(bv[k4*2 + (s>>1)]) : lo64(bv[k4*2 + (s>>1)]);
          acc[k4] = mfma_fp8_32(a[s], bb, acc[k4]);
        }
      }
      #pragma unroll
      for (int i=0; i<8; ++i) bv[i] = *(const uint4*)(wnxt + i*1024);
      // second half: kt8 4..7 (blocks bw)
      #pragma unroll
      for (int s=0; s<4; ++s){
        #pragma unroll
        for (int k4=0; k4<4; ++k4){
          long bb = (s & 1) ? hi64(bw[k4*2 + (s>>1)]) : lo64(bw[k4*2 + (s>>1)]);
          acc[4+k4] = mfma_fp8_32(a[s], bb, acc[4+k4]);
        }
      }
    }
  }

  // ---- phase 3: row softmax over k (true logits = 0.5*acc) ----
  // C layout 32x32: col = lane&31, row = (g&3) + 8*(g>>2) + 4*(lane>>5)
  float gmax[16], gsc[16];
  #pragma unroll
  for (int g=0; g<16; ++g){
    float mx = acc[0][g];
    #pragma unroll
    for (int tt=1; tt<8; ++tt) mx = fmaxf(mx, acc[tt][g]);
    mx = fmaxf(mx, __shfl_xor(mx, 1));
    mx = fmaxf(mx, __shfl_xor(mx, 2));
    mx = fmaxf(mx, __shfl_xor(mx, 4));
    mx = fmaxf(mx, __shfl_xor(mx, 8));
    mx = fmaxf(mx, __shfl_xor(mx, 16));
    if (l32 == 0) redm[(g&3) + 8*(g>>2) + 4*h32][w] = mx;
  }
  __syncthreads();
  #pragma unroll
  for (int g=0; g<16; ++g){
    const int row = (g&3) + 8*(g>>2) + 4*h32;
    float4 u0 = *(const float4*)&redm[row][0];
    float4 u1 = *(const float4*)&redm[row][4];
    gmax[g] = fmaxf(fmaxf(fmaxf(u0.x,u0.y),fmaxf(u0.z,u0.w)),
                    fmaxf(fmaxf(u1.x,u1.y),fmaxf(u1.z,u1.w)));
  }
  #pragma unroll
  for (int g=0; g<16; ++g){
    float s = 0.f;
    #pragma unroll
    for (int tt=0; tt<8; ++tt){
      float e = __expf(0.5f*(acc[tt][g] - gmax[g]));
      acc[tt][g] = e;
      s += e;
    }
    s += __shfl_xor(s, 1);
    s += __shfl_xor(s, 2);
    s += __shfl_xor(s, 4);
    s += __shfl_xor(s, 8);
    s += __shfl_xor(s, 16);
    if (l32 == 0) redsum[(g&3) + 8*(g>>2) + 4*h32][w] = s;
  }
  __syncthreads();
  #pragma unroll
  for (int g=0; g<16; ++g){
    const int row = (g&3) + 8*(g>>2) + 4*h32;
    float4 u0 = *(const float4*)&redsum[row][0];
    float4 u1 = *(const float4*)&redsum[row][4];
    float s = (u0.x+u0.y+u0.z+u0.w) + (u1.x+u1.y+u1.z+u1.w);
    gsc[g] = 256.f/s;
  }
  #pragma unroll
  for (int tt=0; tt<8; ++tt){
    const int col = (w*8 + tt)*32 + l32;
    #pragma unroll
    for (int g=0; g<16; ++g){
      const int row = (g&3) + 8*(g>>2) + 4*h32;
      S[row*SROW8 + col] = f2fp8(acc[tt][g]*gsc[g]);
    }
  }
  __syncthreads();

  // ---- phase 4: out = (deg*256) @ h / 256; e/o split chains; fin fuses final ----
  {
    const int rt4 = w >> 2, dt = w & 3;
    f32x4 oe = {0.f,0.f,0.f,0.f}, oo = {0.f,0.f,0.f,0.f};
    const u8* abase = S + (size_t)(rt4*16 + lc)*SROW8 + q*8;
    const u8* bbase = htb + (size_t)dt*1024 + lane*16;
    uint4 bcur = *(const uint4*)(bbase + (size_t)p0*4096);
    #pragma unroll 1
    for (int pti=0; pti<32; ++pti){
      const int pt = (pti + p0) & 31;
      uint4 bnxt = *(const uint4*)(bbase + (size_t)((pti + 1 + p0)&31)*4096);
      long ae = *(const long*)(abase + pt*64);
      long ao = *(const long*)(abase + pt*64 + 32);
      oe = mfma_fp8(ae, lo64(bcur), oe);
      oo = mfma_fp8(ao, hi64(bcur), oo);
      bcur = bnxt;
    }
    f32x4 o;
    #pragma unroll
    for (int i=0;i<4;i++) o[i] = oe[i] + oo[i];
    float* op = outp + (size_t)b*2048*64;
    const float* hp = hf32 + (size_t)b*2048*64;
    const float* cp = oc_in + (size_t)b*2048*64;
    #pragma unroll
    for (int i=0;i<4;i++){
      size_t idx = (size_t)(n0 + rt4*16 + q*4 + i)*64 + dt*16 + lc;
      float v = o[i]*(1.f/256.f);
      if (fin) v = 0.8f*hp[idx] - 0.1f*cp[idx] + 0.1f*v;
      op[idx] = v;
    }
  }
}

// ---------------------------------------------------------------------------
extern "C" void kernel_launch(void* const* d_in, const int* in_sizes, int n_in,
                              void* d_out, int out_size, void* d_ws, size_t ws_size,
                              hipStream_t stream) {
  const float* x     = (const float*)d_in[0];
  const float* state = (const float*)d_in[1];
  const float* E     = (const float*)d_in[2];
  const float* Wc    = (const float*)d_in[3];
  const float* Wd    = (const float*)d_in[4];
  const float* gw    = (const float*)d_in[5];
  const float* gb    = (const float*)d_in[6];
  const float* uw    = (const float*)d_in[7];
  const float* ub    = (const float*)d_in[8];

  // workspace layout (bytes). Total 73,662,464 B = 70.2 MB.
  char* base = (char*)d_ws;
  u16*   P    = (u16*)(base + 0);           //  8,388,608  (dead after 2nd k_conv)
  u32*   mp2  = (u32*)(base + 0);           //    524,288  (aliases P; written after P dead)
  u32*   mn2  = (u32*)(base + 524288);      //    524,288  (aliases P)
  u8*    msk  = (u8*) (base + 8388608);     //  4,194,304
  u8*    Wc8  = (u8*) (base + 12582912);    //  4,194,304
  u8*    Wd8  = (u8*) (base + 16777216);    //  4,194,304
  u16*   hb16 = (u16*)(base + 20971520);    //  4,194,304
  u8*    ht8p = (u8*) (base + 25165824);    //  2,097,152
  u16*   hfm  = (u16*)(base + 27262976);    //  4,194,304
  float* c1x  = (float*)(base + 31457280);  //    262,144
  float* c1s  = (float*)(base + 31719424);  //  8,388,608
  float* zs   = (float*)(base + 40108032);  //  8,388,608
  float* rws  = (float*)(base + 48496640);  //  8,388,608
  float* c2s  = (float*)(base + 56885248);  //  8,388,608
  float* h    = (float*)(base + 65273856);  //  8,388,608
  float* oc   = c1s;                        // dead after k_gate
  float* od   = c2s;                        // dead after k_upd (unused placeholder)

  k_w8<<<dim3(32,32,2), 256, 0, stream>>>(Wc, Wd, Wc8, Wd8);
  k_P<<<2048, 256, 0, stream>>>(E, P, msk);
  k_c1x<<<dim3(32,16), 128, 0, stream>>>(P, x, c1x);
  k_conv<<<dim3(32,16), 256, 0, stream>>>(P, state, c1s);
  k_gate<<<2048, 256, 0, stream>>>(E, gw, gb, x, state, c1x, c1s, zs, rws);
  k_conv<<<dim3(32,16), 256, 0, stream>>>(P, zs, c2s);
  k_upd<<<2048, 256, 0, stream>>>(E, uw, ub, x, state, zs, c1x, c2s, rws, h);
  k_hcvt<<<dim3(32,16), 256, 0, stream>>>(h, hb16, ht8p, hfm);
  k_mbits<<<dim3(2048,8), 256, 0, stream>>>(msk, mp2, mn2);   // P dead by now

  const int deg_lds = 32*SROW8;   // 65,792 B dynamic
  hipFuncSetAttribute((const void*)k_deg, hipFuncAttributeMaxDynamicSharedMemorySize, deg_lds);
  // dispatch 1: connect mask — only Wc8 hot in every XCD L2
  k_deg<<<1024, 512, deg_lds, stream>>>(mp2, hb16, Wc8, ht8p, hfm, h, h, oc, 0);
  // dispatch 2: disconnect mask — only Wd8 hot; fused final epilogue -> d_out
  k_deg<<<1024, 512, deg_lds, stream>>>(mn2, hb16, Wd8, ht8p, hfm, h, oc, (float*)d_out, 1);
}